// Round 2
// baseline (918.822 us; speedup 1.0000x reference)
//
#include <hip/hip_runtime.h>

// DNAS_DeformAxialDW: out = x + axial-deform-DW-conv_H(x) + axial-deform-DW-conv_W(x)
// Scalar fractional dilation r => each 7-tap conv folds into 13 integer taps with
// per-channel effective weights (precomputed into d_ws by taps_kernel).
// Streaming structure: each thread owns a 7-row x 4-col output strip; input rows
// stream through one register quad and FMA into 7 accumulators. Channel is
// block-uniform so taps live in SGPRs.

namespace {
constexpr int B = 8, C = 128, H = 224, W = 224;
constexpr int KT = 7;            // original taps
constexpr int M  = 6;            // max |integer offset| supported (r in [1,2])
constexpr int NT = 2 * M + 1;    // 13 effective integer taps
constexpr int CH = 7;            // output rows per thread
constexpr int WQ = W / 4;        // 56 float4 quads per row
constexpr int NCH = H / CH;      // 32 chunks per plane
constexpr int TASKS = WQ * NCH;  // 1792 threads per plane
constexpr int BLOCK = 256;
constexpr int BLK_PER_PLANE = TASKS / BLOCK;  // 7, exact
}

// Fold bilinear fractional taps into integer-offset effective weights.
// taps[c*NT + j]        = eh[c][offset j-M]   (H-axis)
// taps[C*NT + c*NT + j] = ew[c][offset j-M]   (W-axis)
__global__ void taps_kernel(const float* __restrict__ wh, const float* __restrict__ ww,
                            const float* __restrict__ r, float* __restrict__ taps) {
    int c = threadIdx.x;
    if (c >= C) return;
    float rv = fmaxf(r[0], 1.0f);  // jnp.clip(r, 1.0)
    float eh[NT], ew[NT];
    for (int j = 0; j < NT; ++j) { eh[j] = 0.f; ew[j] = 0.f; }
    for (int i = 0; i < KT; ++i) {
        float kpos  = (float)(i - KT / 2);
        float delta = kpos * rv;
        float d0f   = floorf(delta);
        float fr    = delta - d0f;
        int   j0    = (int)d0f + M;
        float whv = wh[c * KT + i];
        float wwv = ww[c * KT + i];
        if (j0 >= 0 && j0 < NT)         { eh[j0]   += (1.f - fr) * whv; ew[j0]   += (1.f - fr) * wwv; }
        if (j0 + 1 >= 0 && j0 + 1 < NT) { eh[j0+1] += fr * whv;         ew[j0+1] += fr * wwv; }
    }
    for (int j = 0; j < NT; ++j) {
        taps[c * NT + j]          = eh[j];
        taps[C * NT + c * NT + j] = ew[j];
    }
}

__global__ __launch_bounds__(BLOCK, 8) void deform_axial_kernel(
    const float* __restrict__ x, const float* __restrict__ taps,
    float* __restrict__ out) {
    const int p = blockIdx.y;                  // plane (b*C + c) -- block-uniform
    const int c = p & (C - 1);                 // uniform -> taps via scalar loads
    const int t0 = blockIdx.x * BLOCK + threadIdx.x;  // 0..1791
    const int wq = t0 % WQ;
    const int chunk = t0 / WQ;                 // 0..31
    const int h0 = chunk * CH;

    // per-channel effective taps: block-uniform address -> SGPRs
    float eh[NT], ew[NT];
    const float* __restrict__ ehp = taps + c * NT;
    const float* __restrict__ ewp = taps + C * NT + c * NT;
#pragma unroll
    for (int j = 0; j < NT; ++j) { eh[j] = ehp[j]; ew[j] = ewp[j]; }

    const long base = (long)p * (H * W);
    const float* __restrict__ xp = x + base;
    const float4 zero4 = make_float4(0.f, 0.f, 0.f, 0.f);

    float4 acc[CH];
#pragma unroll
    for (int k = 0; k < CH; ++k) acc[k] = zero4;

    // Stream 19 input rows (h0-6 .. h0+12); each feeds up to 7 accumulators (H-conv).
    // When the streamed row equals an output row (t-6 in [0,CH)), also do the
    // identity add and the W-conv for that row using 4 aligned side quads.
#pragma unroll
    for (int t = 0; t < CH + 2 * M; ++t) {
        const int row = h0 - M + t;
        const bool v = (row >= 0) && (row < H);
        const int rr = v ? row : 0;
        const float* rowp = xp + rr * W + wq * 4;
        float4 q = *reinterpret_cast<const float4*>(rowp);
        if (!v) q = zero4;

        // H-axis: row t contributes tap j = t-k to output row k
#pragma unroll
        for (int k = 0; k < CH; ++k) {
            constexpr_int:;
            const int j = t - k;
            if (j >= 0 && j < NT) {
                const float wgt = eh[j];
                acc[k].x = fmaf(wgt, q.x, acc[k].x);
                acc[k].y = fmaf(wgt, q.y, acc[k].y);
                acc[k].z = fmaf(wgt, q.z, acc[k].z);
                acc[k].w = fmaf(wgt, q.w, acc[k].w);
            }
        }

        // W-axis + identity for output row r = t - M (row is guaranteed in-bounds)
        if (t >= M && t < M + CH) {
            const int r = t - M;
            float4 qm2 = (wq >= 2)      ? *reinterpret_cast<const float4*>(rowp - 8) : zero4;
            float4 qm1 = (wq >= 1)      ? *reinterpret_cast<const float4*>(rowp - 4) : zero4;
            float4 qp1 = (wq <= WQ - 2) ? *reinterpret_cast<const float4*>(rowp + 4) : zero4;
            float4 qp2 = (wq <= WQ - 3) ? *reinterpret_cast<const float4*>(rowp + 8) : zero4;

            float win[20];
            win[ 0] = qm2.x; win[ 1] = qm2.y; win[ 2] = qm2.z; win[ 3] = qm2.w;
            win[ 4] = qm1.x; win[ 5] = qm1.y; win[ 6] = qm1.z; win[ 7] = qm1.w;
            win[ 8] = q.x;   win[ 9] = q.y;   win[10] = q.z;   win[11] = q.w;
            win[12] = qp1.x; win[13] = qp1.y; win[14] = qp1.z; win[15] = qp1.w;
            win[16] = qp2.x; win[17] = qp2.y; win[18] = qp2.z; win[19] = qp2.w;

            // identity
            acc[r].x += q.x; acc[r].y += q.y; acc[r].z += q.z; acc[r].w += q.w;
            // element e at w = wq*4+e, tap j: win index = e + j + 2
#pragma unroll
            for (int j = 0; j < NT; ++j) {
                const float wgt = ew[j];
                acc[r].x = fmaf(wgt, win[2 + j], acc[r].x);
                acc[r].y = fmaf(wgt, win[3 + j], acc[r].y);
                acc[r].z = fmaf(wgt, win[4 + j], acc[r].z);
                acc[r].w = fmaf(wgt, win[5 + j], acc[r].w);
            }
        }
    }

    float* outp = out + base + (long)h0 * W + wq * 4;
#pragma unroll
    for (int k = 0; k < CH; ++k) {
        *reinterpret_cast<float4*>(outp + k * W) = acc[k];
    }
}

extern "C" void kernel_launch(void* const* d_in, const int* in_sizes, int n_in,
                              void* d_out, int out_size, void* d_ws, size_t ws_size,
                              hipStream_t stream) {
    const float* x  = (const float*)d_in[0];
    const float* wh = (const float*)d_in[1];
    const float* ww = (const float*)d_in[2];
    const float* r  = (const float*)d_in[3];
    float* out  = (float*)d_out;
    float* taps = (float*)d_ws;  // needs 2*C*NT*4 = 13,312 bytes

    hipLaunchKernelGGL(taps_kernel, dim3(1), dim3(C), 0, stream, wh, ww, r, taps);
    hipLaunchKernelGGL(deform_axial_kernel, dim3(BLK_PER_PLANE, B * C), dim3(BLOCK),
                       0, stream, x, taps, out);
}

// Round 3
// 429.275 us; speedup vs baseline: 2.1404x; 2.1404x over previous
//
#include <hip/hip_runtime.h>

// DNAS_DeformAxialDW: out = x + axial-deform-DW-conv_H(x) + axial-deform-DW-conv_W(x)
// Scalar fractional dilation r => each 7-tap conv folds into 13 integer taps with
// per-channel effective weights (precomputed into d_ws by taps_kernel).
// Streaming structure: each thread owns a 7-row x 4-col output strip; input rows
// stream through one register quad and FMA into 7 accumulators. Channel is
// block-uniform so taps live in SGPRs.
//
// R2 lesson: __launch_bounds__(256,8) clamped VGPR to 32 -> acc spilled to
// scratch (WRITE_SIZE 2 GB, 919 us). Use (256,4): 128-VGPR cap, no spill.

namespace {
constexpr int B = 8, C = 128, H = 224, W = 224;
constexpr int KT = 7;            // original taps
constexpr int M  = 6;            // max |integer offset| supported (r in [1,2])
constexpr int NT = 2 * M + 1;    // 13 effective integer taps
constexpr int CH = 7;            // output rows per thread
constexpr int WQ = W / 4;        // 56 float4 quads per row
constexpr int NCH = H / CH;      // 32 chunks per plane
constexpr int TASKS = WQ * NCH;  // 1792 threads per plane
constexpr int BLOCK = 256;
constexpr int BLK_PER_PLANE = TASKS / BLOCK;  // 7, exact
}

// Fold bilinear fractional taps into integer-offset effective weights.
// taps[c*NT + j]        = eh[c][offset j-M]   (H-axis)
// taps[C*NT + c*NT + j] = ew[c][offset j-M]   (W-axis)
__global__ void taps_kernel(const float* __restrict__ wh, const float* __restrict__ ww,
                            const float* __restrict__ r, float* __restrict__ taps) {
    int c = threadIdx.x;
    if (c >= C) return;
    float rv = fmaxf(r[0], 1.0f);  // jnp.clip(r, 1.0)
    float eh[NT], ew[NT];
    for (int j = 0; j < NT; ++j) { eh[j] = 0.f; ew[j] = 0.f; }
    for (int i = 0; i < KT; ++i) {
        float kpos  = (float)(i - KT / 2);
        float delta = kpos * rv;
        float d0f   = floorf(delta);
        float fr    = delta - d0f;
        int   j0    = (int)d0f + M;
        float whv = wh[c * KT + i];
        float wwv = ww[c * KT + i];
        if (j0 >= 0 && j0 < NT)         { eh[j0]   += (1.f - fr) * whv; ew[j0]   += (1.f - fr) * wwv; }
        if (j0 + 1 >= 0 && j0 + 1 < NT) { eh[j0+1] += fr * whv;         ew[j0+1] += fr * wwv; }
    }
    for (int j = 0; j < NT; ++j) {
        taps[c * NT + j]          = eh[j];
        taps[C * NT + c * NT + j] = ew[j];
    }
}

__global__ __launch_bounds__(BLOCK, 4) void deform_axial_kernel(
    const float* __restrict__ x, const float* __restrict__ taps,
    float* __restrict__ out) {
    const int p = blockIdx.y;                  // plane (b*C + c) -- block-uniform
    const int c = p & (C - 1);                 // uniform -> taps via scalar loads
    const int t0 = blockIdx.x * BLOCK + threadIdx.x;  // 0..1791
    const int wq = t0 % WQ;
    const int chunk = t0 / WQ;                 // 0..31
    const int h0 = chunk * CH;

    // per-channel effective taps: block-uniform address -> SGPRs
    float eh[NT], ew[NT];
    const float* __restrict__ ehp = taps + c * NT;
    const float* __restrict__ ewp = taps + C * NT + c * NT;
#pragma unroll
    for (int j = 0; j < NT; ++j) { eh[j] = ehp[j]; ew[j] = ewp[j]; }

    const long base = (long)p * (H * W);
    const float* __restrict__ xp = x + base;
    const float4 zero4 = make_float4(0.f, 0.f, 0.f, 0.f);

    float4 acc[CH];
#pragma unroll
    for (int k = 0; k < CH; ++k) acc[k] = zero4;

    // Stream 19 input rows (h0-6 .. h0+12); each feeds up to 7 accumulators (H-conv).
    // When the streamed row is an output row (t-6 in [0,CH)), also do the identity
    // add and the W-conv for that row using 4 aligned side quads.
#pragma unroll
    for (int t = 0; t < CH + 2 * M; ++t) {
        const int row = h0 - M + t;
        const bool v = (row >= 0) && (row < H);
        const int rr = v ? row : 0;
        const float* rowp = xp + rr * W + wq * 4;
        float4 q = *reinterpret_cast<const float4*>(rowp);
        if (!v) q = zero4;

        // H-axis: streamed row t contributes tap j = t-k to output row k
#pragma unroll
        for (int k = 0; k < CH; ++k) {
            const int j = t - k;
            if (j >= 0 && j < NT) {
                const float wgt = eh[j];
                acc[k].x = fmaf(wgt, q.x, acc[k].x);
                acc[k].y = fmaf(wgt, q.y, acc[k].y);
                acc[k].z = fmaf(wgt, q.z, acc[k].z);
                acc[k].w = fmaf(wgt, q.w, acc[k].w);
            }
        }

        // W-axis + identity for output row r = t - M (row guaranteed in-bounds)
        if (t >= M && t < M + CH) {
            const int r = t - M;
            float4 qm2 = (wq >= 2)      ? *reinterpret_cast<const float4*>(rowp - 8) : zero4;
            float4 qm1 = (wq >= 1)      ? *reinterpret_cast<const float4*>(rowp - 4) : zero4;
            float4 qp1 = (wq <= WQ - 2) ? *reinterpret_cast<const float4*>(rowp + 4) : zero4;
            float4 qp2 = (wq <= WQ - 3) ? *reinterpret_cast<const float4*>(rowp + 8) : zero4;

            float win[20];
            win[ 0] = qm2.x; win[ 1] = qm2.y; win[ 2] = qm2.z; win[ 3] = qm2.w;
            win[ 4] = qm1.x; win[ 5] = qm1.y; win[ 6] = qm1.z; win[ 7] = qm1.w;
            win[ 8] = q.x;   win[ 9] = q.y;   win[10] = q.z;   win[11] = q.w;
            win[12] = qp1.x; win[13] = qp1.y; win[14] = qp1.z; win[15] = qp1.w;
            win[16] = qp2.x; win[17] = qp2.y; win[18] = qp2.z; win[19] = qp2.w;

            // identity
            acc[r].x += q.x; acc[r].y += q.y; acc[r].z += q.z; acc[r].w += q.w;
            // element e at w = wq*4+e, tap j: win index = e + j + 2
#pragma unroll
            for (int j = 0; j < NT; ++j) {
                const float wgt = ew[j];
                acc[r].x = fmaf(wgt, win[2 + j], acc[r].x);
                acc[r].y = fmaf(wgt, win[3 + j], acc[r].y);
                acc[r].z = fmaf(wgt, win[4 + j], acc[r].z);
                acc[r].w = fmaf(wgt, win[5 + j], acc[r].w);
            }
        }
    }

    float* outp = out + base + (long)h0 * W + wq * 4;
#pragma unroll
    for (int k = 0; k < CH; ++k) {
        *reinterpret_cast<float4*>(outp + k * W) = acc[k];
    }
}

extern "C" void kernel_launch(void* const* d_in, const int* in_sizes, int n_in,
                              void* d_out, int out_size, void* d_ws, size_t ws_size,
                              hipStream_t stream) {
    const float* x  = (const float*)d_in[0];
    const float* wh = (const float*)d_in[1];
    const float* ww = (const float*)d_in[2];
    const float* r  = (const float*)d_in[3];
    float* out  = (float*)d_out;
    float* taps = (float*)d_ws;  // needs 2*C*NT*4 = 13,312 bytes

    hipLaunchKernelGGL(taps_kernel, dim3(1), dim3(C), 0, stream, wh, ww, r, taps);
    hipLaunchKernelGGL(deform_axial_kernel, dim3(BLK_PER_PLANE, B * C), dim3(BLOCK),
                       0, stream, x, taps, out);
}

// Round 4
// 212.849 us; speedup vs baseline: 4.3168x; 2.0168x over previous
//
#include <hip/hip_runtime.h>

// DNAS_DeformAxialDW: out = x + axial-deform-DW-conv_H(x) + axial-deform-DW-conv_W(x)
// Scalar fractional dilation r => each 7-tap conv folds into 13 integer taps with
// per-channel effective weights (precomputed into d_ws by taps_kernel).
//
// R1 lesson: register row-window => latency-bound (L2/L3-serving dependent loads,
//            few waves, 214 us). R2/R3 lesson: big unrolled streaming loop =>
//            compiler hoists loads, spills to scratch (WRITE_SIZE 2GB/968MB).
// R4: LDS-staged full-width tile. Stage 44x224 slab with bulk coalesced loads
//     (high MLP, amortized by barrier), compute purely from LDS with tiny
//     register state. 39.4 KB LDS -> 4 blocks/CU; block = 448 thr (7 waves).

namespace {
constexpr int B = 8, C = 128, H = 224, W = 224;
constexpr int KT = 7;              // original taps
constexpr int M  = 6;              // max |integer offset| (r in [1,2])
constexpr int NT = 2 * M + 1;      // 13 effective integer taps
constexpr int TH = 32;             // output rows per tile
constexpr int HTILES = H / TH;     // 7
constexpr int SROWS = TH + 2 * M;  // 44 staged rows
constexpr int WQ = W / 4;          // 56 quads per row
constexpr int BLOCK = 448;         // 7 waves; 56 cols x 8 row-groups
constexpr int RPT = TH / (BLOCK / WQ);   // 4 output rows per thread
constexpr int NSTAGE = SROWS * WQ; // 2464 staging quads
constexpr int STAGE_IT = (NSTAGE + BLOCK - 1) / BLOCK;  // 6
}

// Fold bilinear fractional taps into integer-offset effective weights.
// taps[c*NT + j]        = eh[c][offset j-M]   (H-axis)
// taps[C*NT + c*NT + j] = ew[c][offset j-M]   (W-axis)
__global__ void taps_kernel(const float* __restrict__ wh, const float* __restrict__ ww,
                            const float* __restrict__ r, float* __restrict__ taps) {
    int c = threadIdx.x;
    if (c >= C) return;
    float rv = fmaxf(r[0], 1.0f);  // jnp.clip(r, 1.0)
    float eh[NT], ew[NT];
    for (int j = 0; j < NT; ++j) { eh[j] = 0.f; ew[j] = 0.f; }
    for (int i = 0; i < KT; ++i) {
        float kpos  = (float)(i - KT / 2);
        float delta = kpos * rv;
        float d0f   = floorf(delta);
        float fr    = delta - d0f;
        int   j0    = (int)d0f + M;
        float whv = wh[c * KT + i];
        float wwv = ww[c * KT + i];
        if (j0 >= 0 && j0 < NT)         { eh[j0]   += (1.f - fr) * whv; ew[j0]   += (1.f - fr) * wwv; }
        if (j0 + 1 >= 0 && j0 + 1 < NT) { eh[j0+1] += fr * whv;         ew[j0+1] += fr * wwv; }
    }
    for (int j = 0; j < NT; ++j) {
        taps[c * NT + j]          = eh[j];
        taps[C * NT + c * NT + j] = ew[j];
    }
}

__global__ __launch_bounds__(BLOCK) void deform_axial_kernel(
    const float* __restrict__ x, const float* __restrict__ taps,
    float* __restrict__ out) {
    __shared__ float lds[SROWS][W];   // 44 x 224 x 4B = 39,424 B

    const int p    = blockIdx.y;       // plane (b*C + c) -- block-uniform
    const int c    = p & (C - 1);      // uniform -> taps via scalar loads
    const int h0   = blockIdx.x * TH;  // tile's first output row
    const int tid  = threadIdx.x;

    // per-channel effective taps: block-uniform address -> SGPRs
    float eh[NT], ew[NT];
    const float* __restrict__ ehp = taps + c * NT;
    const float* __restrict__ ewp = taps + C * NT + c * NT;
#pragma unroll
    for (int j = 0; j < NT; ++j) { eh[j] = ehp[j]; ew[j] = ewp[j]; }

    const long base = (long)p * (H * W);
    const float* __restrict__ xp = x + base;
    const float4 zero4 = make_float4(0.f, 0.f, 0.f, 0.f);

    // ---- stage: rows h0-6 .. h0+37 into LDS (zero outside [0,H)) ----
#pragma unroll
    for (int k = 0; k < STAGE_IT; ++k) {
        const int q = tid + k * BLOCK;
        if (q < NSTAGE) {
            const int row = q / WQ;
            const int col = q % WQ;
            const int gr  = h0 - M + row;
            float4 v = zero4;
            if (gr >= 0 && gr < H)
                v = *reinterpret_cast<const float4*>(xp + gr * W + col * 4);
            *reinterpret_cast<float4*>(&lds[row][col * 4]) = v;
        }
    }
    __syncthreads();

    // ---- compute: thread owns 4 output rows x 1 quad ----
    const int cq = tid % WQ;        // column quad 0..55
    const int rg = tid / WQ;        // row group 0..7
    const int r0 = rg * RPT;

#pragma unroll
    for (int i = 0; i < RPT; ++i) {
        const int orow = r0 + i;    // output row within tile, 0..31
        // center quad (LDS row orow+6 holds global row h0+orow)
        const float4 q6 = *reinterpret_cast<const float4*>(&lds[orow + M][cq * 4]);
        float4 acc = q6;            // identity term

        // H-axis: 13 taps down the column (LDS rows orow .. orow+12)
#pragma unroll
        for (int j = 0; j < NT; ++j) {
            const float4 qv = *reinterpret_cast<const float4*>(&lds[orow + j][cq * 4]);
            const float wgt = eh[j];
            acc.x = fmaf(wgt, qv.x, acc.x);
            acc.y = fmaf(wgt, qv.y, acc.y);
            acc.z = fmaf(wgt, qv.z, acc.z);
            acc.w = fmaf(wgt, qv.w, acc.w);
        }

        // W-axis: 20-float window = quads cq-2 .. cq+2 of the center row
        const float* crow = &lds[orow + M][0];
        float4 qm2 = (cq >= 2)      ? *reinterpret_cast<const float4*>(crow + (cq - 2) * 4) : zero4;
        float4 qm1 = (cq >= 1)      ? *reinterpret_cast<const float4*>(crow + (cq - 1) * 4) : zero4;
        float4 qp1 = (cq <= WQ - 2) ? *reinterpret_cast<const float4*>(crow + (cq + 1) * 4) : zero4;
        float4 qp2 = (cq <= WQ - 3) ? *reinterpret_cast<const float4*>(crow + (cq + 2) * 4) : zero4;

        float win[20];
        win[ 0] = qm2.x; win[ 1] = qm2.y; win[ 2] = qm2.z; win[ 3] = qm2.w;
        win[ 4] = qm1.x; win[ 5] = qm1.y; win[ 6] = qm1.z; win[ 7] = qm1.w;
        win[ 8] = q6.x;  win[ 9] = q6.y;  win[10] = q6.z;  win[11] = q6.w;
        win[12] = qp1.x; win[13] = qp1.y; win[14] = qp1.z; win[15] = qp1.w;
        win[16] = qp2.x; win[17] = qp2.y; win[18] = qp2.z; win[19] = qp2.w;

        // element e at w = cq*4+e, tap j: win index = e + j + 2
#pragma unroll
        for (int j = 0; j < NT; ++j) {
            const float wgt = ew[j];
            acc.x = fmaf(wgt, win[2 + j], acc.x);
            acc.y = fmaf(wgt, win[3 + j], acc.y);
            acc.z = fmaf(wgt, win[4 + j], acc.z);
            acc.w = fmaf(wgt, win[5 + j], acc.w);
        }

        *reinterpret_cast<float4*>(out + base + (long)(h0 + orow) * W + cq * 4) = acc;
    }
}

extern "C" void kernel_launch(void* const* d_in, const int* in_sizes, int n_in,
                              void* d_out, int out_size, void* d_ws, size_t ws_size,
                              hipStream_t stream) {
    const float* x  = (const float*)d_in[0];
    const float* wh = (const float*)d_in[1];
    const float* ww = (const float*)d_in[2];
    const float* r  = (const float*)d_in[3];
    float* out  = (float*)d_out;
    float* taps = (float*)d_ws;  // needs 2*C*NT*4 = 13,312 bytes

    hipLaunchKernelGGL(taps_kernel, dim3(1), dim3(C), 0, stream, wh, ww, r, taps);
    hipLaunchKernelGGL(deform_axial_kernel, dim3(HTILES, B * C), dim3(BLOCK),
                       0, stream, x, taps, out);
}

// Round 5
// 145.155 us; speedup vs baseline: 6.3299x; 1.4664x over previous
//
#include <hip/hip_runtime.h>

// DNAS_DeformAxialDW: out = x + axial-deform-DW-conv_H(x) + axial-deform-DW-conv_W(x)
// Scalar fractional dilation r => each 7-tap conv folds into 13 integer taps with
// per-channel effective weights (precomputed into d_ws by taps_kernel).
//
// R1: register row-window -> L2-latency bound (214 us). R2/R3: global streaming
//     -> compiler hoists global loads, spills (2GB/968MB scratch). R4: LDS tile,
//     but 18 ds_read_b128 per output quad -> LDS-pipe bound (~70us issue + 52us
//     conflicts) -> 213 us.
// R5: same LDS tile, but STREAM the 16 window rows once through registers and
//     accumulate into 4 row-accumulators (vertical reuse): 8 reads/quad instead
//     of 18. LDS issue ~31 us; HBM ~55-75 us becomes the floor.

namespace {
constexpr int B = 8, C = 128, H = 224, W = 224;
constexpr int KT = 7;              // original taps
constexpr int M  = 6;              // max |integer offset| (r in [1,2])
constexpr int NT = 2 * M + 1;      // 13 effective integer taps
constexpr int TH = 32;             // output rows per tile
constexpr int HTILES = H / TH;     // 7
constexpr int SROWS = TH + 2 * M;  // 44 staged rows
constexpr int WQ = W / 4;          // 56 quads per row
constexpr int BLOCK = 448;         // 7 waves; 56 cols x 8 row-groups
constexpr int RPT = 4;             // output rows per thread
constexpr int WROWS = RPT + 2 * M; // 16 window rows per thread
constexpr int NSTAGE = SROWS * WQ; // 2464 staging quads
constexpr int STAGE_IT = (NSTAGE + BLOCK - 1) / BLOCK;  // 6
}

// Fold bilinear fractional taps into integer-offset effective weights.
// taps[c*NT + j]        = eh[c][offset j-M]   (H-axis)
// taps[C*NT + c*NT + j] = ew[c][offset j-M]   (W-axis)
__global__ void taps_kernel(const float* __restrict__ wh, const float* __restrict__ ww,
                            const float* __restrict__ r, float* __restrict__ taps) {
    int c = threadIdx.x;
    if (c >= C) return;
    float rv = fmaxf(r[0], 1.0f);  // jnp.clip(r, 1.0)
    float eh[NT], ew[NT];
    for (int j = 0; j < NT; ++j) { eh[j] = 0.f; ew[j] = 0.f; }
    for (int i = 0; i < KT; ++i) {
        float kpos  = (float)(i - KT / 2);
        float delta = kpos * rv;
        float d0f   = floorf(delta);
        float fr    = delta - d0f;
        int   j0    = (int)d0f + M;
        float whv = wh[c * KT + i];
        float wwv = ww[c * KT + i];
        if (j0 >= 0 && j0 < NT)         { eh[j0]   += (1.f - fr) * whv; ew[j0]   += (1.f - fr) * wwv; }
        if (j0 + 1 >= 0 && j0 + 1 < NT) { eh[j0+1] += fr * whv;         ew[j0+1] += fr * wwv; }
    }
    for (int j = 0; j < NT; ++j) {
        taps[c * NT + j]          = eh[j];
        taps[C * NT + c * NT + j] = ew[j];
    }
}

__global__ __launch_bounds__(BLOCK) void deform_axial_kernel(
    const float* __restrict__ x, const float* __restrict__ taps,
    float* __restrict__ out) {
    __shared__ float lds[SROWS][W];   // 44 x 224 x 4B = 39,424 B -> 4 blocks/CU

    const int p    = blockIdx.y;       // plane (b*C + c) -- block-uniform
    const int c    = p & (C - 1);      // uniform -> taps via scalar loads
    const int h0   = blockIdx.x * TH;  // tile's first output row
    const int tid  = threadIdx.x;

    // per-channel effective taps: block-uniform address -> SGPRs
    float eh[NT], ew[NT];
    const float* __restrict__ ehp = taps + c * NT;
    const float* __restrict__ ewp = taps + C * NT + c * NT;
#pragma unroll
    for (int j = 0; j < NT; ++j) { eh[j] = ehp[j]; ew[j] = ewp[j]; }

    const long base = (long)p * (H * W);
    const float* __restrict__ xp = x + base;
    const float4 zero4 = make_float4(0.f, 0.f, 0.f, 0.f);

    // ---- stage: rows h0-6 .. h0+37 into LDS (zero outside [0,H)) ----
#pragma unroll
    for (int k = 0; k < STAGE_IT; ++k) {
        const int q = tid + k * BLOCK;
        if (q < NSTAGE) {
            const int row = q / WQ;
            const int col = q % WQ;
            const int gr  = h0 - M + row;
            float4 v = zero4;
            if (gr >= 0 && gr < H)
                v = *reinterpret_cast<const float4*>(xp + gr * W + col * 4);
            *reinterpret_cast<float4*>(&lds[row][col * 4]) = v;
        }
    }
    __syncthreads();

    // ---- compute: thread owns 4 consecutive output rows x 1 quad ----
    // Stream window rows once; each feeds <=4 accumulators (H-conv). When the
    // streamed row is a center row (t-6 in [0,RPT)), add identity + W-conv.
    const int cq = tid % WQ;        // column quad 0..55
    const int rg = tid / WQ;        // row group 0..7
    const int r0 = rg * RPT;        // first output row (within tile), 0..28

    float4 acc[RPT];
#pragma unroll
    for (int k = 0; k < RPT; ++k) acc[k] = zero4;

#pragma unroll
    for (int t = 0; t < WROWS; ++t) {
        // LDS row r0+t holds global row h0 + r0 + t - 6 (output row r0+k uses
        // LDS rows r0+k .. r0+k+12 for taps j=0..12)
        const float4 q = *reinterpret_cast<const float4*>(&lds[r0 + t][cq * 4]);

        // H-axis: streamed row t is tap j = t-k for output row k
#pragma unroll
        for (int k = 0; k < RPT; ++k) {
            const int j = t - k;
            if (j >= 0 && j < NT) {
                const float wgt = eh[j];
                acc[k].x = fmaf(wgt, q.x, acc[k].x);
                acc[k].y = fmaf(wgt, q.y, acc[k].y);
                acc[k].z = fmaf(wgt, q.z, acc[k].z);
                acc[k].w = fmaf(wgt, q.w, acc[k].w);
            }
        }

        // center row for output k = t - M: identity + W-conv
        if (t >= M && t < M + RPT) {
            const int k = t - M;
            const float* crow = &lds[r0 + t][0];
            float4 qm2 = (cq >= 2)      ? *reinterpret_cast<const float4*>(crow + (cq - 2) * 4) : zero4;
            float4 qm1 = (cq >= 1)      ? *reinterpret_cast<const float4*>(crow + (cq - 1) * 4) : zero4;
            float4 qp1 = (cq <= WQ - 2) ? *reinterpret_cast<const float4*>(crow + (cq + 1) * 4) : zero4;
            float4 qp2 = (cq <= WQ - 3) ? *reinterpret_cast<const float4*>(crow + (cq + 2) * 4) : zero4;

            float win[20];
            win[ 0] = qm2.x; win[ 1] = qm2.y; win[ 2] = qm2.z; win[ 3] = qm2.w;
            win[ 4] = qm1.x; win[ 5] = qm1.y; win[ 6] = qm1.z; win[ 7] = qm1.w;
            win[ 8] = q.x;   win[ 9] = q.y;   win[10] = q.z;   win[11] = q.w;
            win[12] = qp1.x; win[13] = qp1.y; win[14] = qp1.z; win[15] = qp1.w;
            win[16] = qp2.x; win[17] = qp2.y; win[18] = qp2.z; win[19] = qp2.w;

            // identity
            acc[k].x += q.x; acc[k].y += q.y; acc[k].z += q.z; acc[k].w += q.w;
            // element e at w = cq*4+e, tap j: win index = e + j + 2
#pragma unroll
            for (int j = 0; j < NT; ++j) {
                const float wgt = ew[j];
                acc[k].x = fmaf(wgt, win[2 + j], acc[k].x);
                acc[k].y = fmaf(wgt, win[3 + j], acc[k].y);
                acc[k].z = fmaf(wgt, win[4 + j], acc[k].z);
                acc[k].w = fmaf(wgt, win[5 + j], acc[k].w);
            }
        }
    }

    float* outp = out + base + (long)(h0 + r0) * W + cq * 4;
#pragma unroll
    for (int k = 0; k < RPT; ++k) {
        *reinterpret_cast<float4*>(outp + k * W) = acc[k];
    }
}

extern "C" void kernel_launch(void* const* d_in, const int* in_sizes, int n_in,
                              void* d_out, int out_size, void* d_ws, size_t ws_size,
                              hipStream_t stream) {
    const float* x  = (const float*)d_in[0];
    const float* wh = (const float*)d_in[1];
    const float* ww = (const float*)d_in[2];
    const float* r  = (const float*)d_in[3];
    float* out  = (float*)d_out;
    float* taps = (float*)d_ws;  // needs 2*C*NT*4 = 13,312 bytes

    hipLaunchKernelGGL(taps_kernel, dim3(1), dim3(C), 0, stream, wh, ww, r, taps);
    hipLaunchKernelGGL(deform_axial_kernel, dim3(HTILES, B * C), dim3(BLOCK),
                       0, stream, x, taps, out);
}